// Round 2
// baseline (167.071 us; speedup 1.0000x reference)
//
#include <hip/hip_runtime.h>
#include <hip/hip_bf16.h>

#define B_ 4
#define N_ 4096
#define D_ 128

typedef short short8 __attribute__((ext_vector_type(8)));
typedef float f32x4 __attribute__((ext_vector_type(4)));

// ---------------------------------------------------------------------------
// Kernel 1: fp32 -> bf16 convert (RTN-E), row squared-norms, init min arrays.
// One block per row (128 threads = 1 element each). blockIdx.y: 0=X, 1=Y.
// ---------------------------------------------------------------------------
__global__ __launch_bounds__(128) void prep_kernel(
    const float* __restrict__ X, const float* __restrict__ Y,
    unsigned short* __restrict__ Xb, unsigned short* __restrict__ Yb,
    float* __restrict__ x2, float* __restrict__ y2,
    int* __restrict__ rowmin, int* __restrict__ colmin)
{
    const int row = blockIdx.x;              // 0 .. B_*N_-1
    const int which = blockIdx.y;            // 0 = X (pred), 1 = Y (target)
    const int tid = threadIdx.x;             // 0..127

    const float* src = which ? Y : X;
    unsigned short* dst = which ? Yb : Xb;
    float* nrm = which ? y2 : x2;
    int* mn = which ? colmin : rowmin;

    const float v = src[(size_t)row * D_ + tid];
    // round-to-nearest-even bf16 conversion
    const unsigned u = __float_as_uint(v);
    const unsigned r = (u + 0x7fffu + ((u >> 16) & 1u)) >> 16;
    dst[(size_t)row * D_ + tid] = (unsigned short)r;

    float sq = v * v;
    #pragma unroll
    for (int m = 1; m < 64; m <<= 1) sq += __shfl_xor(sq, m);
    __shared__ float s2[2];
    if ((tid & 63) == 0) s2[tid >> 6] = sq;
    __syncthreads();
    if (tid == 0) {
        nrm[row] = s2[0] + s2[1];
        mn[row] = 0x7f7fffff;   // FLT_MAX bit pattern (positive -> int order == float order)
    }
}

// ---------------------------------------------------------------------------
// Kernel 2: tiled bf16 MFMA distance + online min reduction.
// Block = 256 thr = 4 waves; block tile 128x128; wave tile 64x64 (4x4 MFMA
// tiles of 16x16, K=32 per mfma, 4 K-chunks). Fragments loaded straight from
// global (L2-resident: 2 MB/batch). gemm_bt: a/b frags load identically.
//   A-frag: X[row0 + (lane&15)][kc + (lane>>4)*8 + j]
//   B-frag: Y[col0 + (lane&15)][kc + (lane>>4)*8 + j]
//   C/D:    row = (lane>>4)*4 + reg, col = lane&15   [m89-verified layout]
// ---------------------------------------------------------------------------
__global__ __launch_bounds__(256) void chamfer_mfma(
    const unsigned short* __restrict__ Xb, const unsigned short* __restrict__ Yb,
    const float* __restrict__ x2, const float* __restrict__ y2,
    int* __restrict__ rowmin, int* __restrict__ colmin)
{
    const int b = blockIdx.z;
    const int iT = blockIdx.y, jT = blockIdx.x;
    const int tid = threadIdx.x;
    const int wave = tid >> 6, lane = tid & 63;
    const int quad = lane >> 4, l16 = lane & 15;
    const int wr = wave >> 1, wc = wave & 1;
    const int rowBase = iT * 128 + wr * 64;
    const int colBase = jT * 128 + wc * 64;

    const unsigned short* Xp = Xb + (size_t)b * N_ * D_;
    const unsigned short* Yp = Yb + (size_t)b * N_ * D_;

    f32x4 acc[4][4];
    #pragma unroll
    for (int i = 0; i < 4; i++)
        #pragma unroll
        for (int j = 0; j < 4; j++)
            acc[i][j] = (f32x4){0.f, 0.f, 0.f, 0.f};

    #pragma unroll
    for (int kc = 0; kc < D_; kc += 32) {
        const int koff = kc + quad * 8;
        short8 af[4], bfv[4];
        #pragma unroll
        for (int rt = 0; rt < 4; rt++)
            af[rt] = *(const short8*)(Xp + (size_t)(rowBase + rt * 16 + l16) * D_ + koff);
        #pragma unroll
        for (int ct = 0; ct < 4; ct++)
            bfv[ct] = *(const short8*)(Yp + (size_t)(colBase + ct * 16 + l16) * D_ + koff);
        #pragma unroll
        for (int rt = 0; rt < 4; rt++)
            #pragma unroll
            for (int ct = 0; ct < 4; ct++)
                acc[rt][ct] = __builtin_amdgcn_mfma_f32_16x16x32_bf16(
                    af[rt], bfv[ct], acc[rt][ct], 0, 0, 0);
    }

    // ---- epilogue: P = x2[row] + y2[col] - 2*zz, clip [0,100], min-reduce ----
    float x2v[4][4];   // [rt][reg] -> row = rowBase + rt*16 + quad*4 + reg
    #pragma unroll
    for (int rt = 0; rt < 4; rt++)
        #pragma unroll
        for (int i = 0; i < 4; i++)
            x2v[rt][i] = x2[(size_t)b * N_ + rowBase + rt * 16 + quad * 4 + i];
    float y2v[4];      // [ct] -> col = colBase + ct*16 + l16
    #pragma unroll
    for (int ct = 0; ct < 4; ct++)
        y2v[ct] = y2[(size_t)b * N_ + colBase + ct * 16 + l16];

    float rmin[4][4];
    float cmin[4];
    #pragma unroll
    for (int ct = 0; ct < 4; ct++) cmin[ct] = 3.0e38f;
    #pragma unroll
    for (int rt = 0; rt < 4; rt++)
        #pragma unroll
        for (int i = 0; i < 4; i++) {
            float m = 3.0e38f;
            #pragma unroll
            for (int ct = 0; ct < 4; ct++) {
                float p = x2v[rt][i] + y2v[ct] - 2.0f * acc[rt][ct][i];
                p = fminf(fmaxf(p, 0.0f), 100.0f);
                m = fminf(m, p);
                cmin[ct] = fminf(cmin[ct], p);
            }
            rmin[rt][i] = m;
        }

    // rowmin: min over columns -> reduce across the 16 lanes of each quad
    #pragma unroll
    for (int rt = 0; rt < 4; rt++)
        #pragma unroll
        for (int i = 0; i < 4; i++) {
            float v = rmin[rt][i];
            #pragma unroll
            for (int m = 1; m < 16; m <<= 1) v = fminf(v, __shfl_xor(v, m));
            rmin[rt][i] = v;
        }
    if (l16 == 0) {
        #pragma unroll
        for (int rt = 0; rt < 4; rt++)
            #pragma unroll
            for (int i = 0; i < 4; i++)
                atomicMin(&rowmin[(size_t)b * N_ + rowBase + rt * 16 + quad * 4 + i],
                          __float_as_int(rmin[rt][i]));
    }

    // colmin: min over rows -> reduce across quads (xor 16, 32)
    #pragma unroll
    for (int ct = 0; ct < 4; ct++) {
        float v = cmin[ct];
        v = fminf(v, __shfl_xor(v, 16));
        v = fminf(v, __shfl_xor(v, 32));
        cmin[ct] = v;
    }
    if (quad == 0) {
        #pragma unroll
        for (int ct = 0; ct < 4; ct++)
            atomicMin(&colmin[(size_t)b * N_ + colBase + ct * 16 + l16],
                      __float_as_int(cmin[ct]));
    }
}

// ---------------------------------------------------------------------------
// Kernel 3: final mean. mins = rowmin (B_*N_) followed immediately by
// colmin (B_*N_) in the workspace layout.
// out = (sum_rowmin + sum_colmin) / (B*N) / B
// ---------------------------------------------------------------------------
__global__ __launch_bounds__(256) void finalize_kernel(
    const int* __restrict__ mins, float* __restrict__ out)
{
    float s = 0.f;
    const int4* p = (const int4*)mins;
    const int n4 = (2 * B_ * N_) / 4;
    for (int i = threadIdx.x; i < n4; i += 256) {
        int4 v = p[i];
        s += __int_as_float(v.x) + __int_as_float(v.y) +
             __int_as_float(v.z) + __int_as_float(v.w);
    }
    #pragma unroll
    for (int m = 1; m < 64; m <<= 1) s += __shfl_xor(s, m);
    __shared__ float sm[4];
    if ((threadIdx.x & 63) == 0) sm[threadIdx.x >> 6] = s;
    __syncthreads();
    if (threadIdx.x == 0)
        out[0] = (sm[0] + sm[1] + sm[2] + sm[3]) / ((float)B_ * (float)N_) / (float)B_;
}

extern "C" void kernel_launch(void* const* d_in, const int* in_sizes, int n_in,
                              void* d_out, int out_size, void* d_ws, size_t ws_size,
                              hipStream_t stream) {
    const float* X = (const float*)d_in[0];   // corr_pred  [B,N,D] fp32
    const float* Y = (const float*)d_in[1];   // corr_target [B,N,D] fp32

    char* ws = (char*)d_ws;
    const size_t bf_bytes = (size_t)B_ * N_ * D_ * 2;   // 4 MB each
    unsigned short* Xb = (unsigned short*)ws;
    unsigned short* Yb = (unsigned short*)(ws + bf_bytes);
    char* ws2 = ws + 2 * bf_bytes;
    const size_t vec_bytes = (size_t)B_ * N_ * 4;       // 64 KB each
    float* x2     = (float*)(ws2);
    float* y2     = (float*)(ws2 + vec_bytes);
    int*   rowmin = (int*)  (ws2 + 2 * vec_bytes);
    int*   colmin = (int*)  (ws2 + 3 * vec_bytes);      // contiguous after rowmin
    float* out = (float*)d_out;

    prep_kernel<<<dim3(B_ * N_, 2), 128, 0, stream>>>(X, Y, Xb, Yb, x2, y2, rowmin, colmin);
    chamfer_mfma<<<dim3(N_ / 128, N_ / 128, B_), 256, 0, stream>>>(Xb, Yb, x2, y2, rowmin, colmin);
    finalize_kernel<<<1, 256, 0, stream>>>(rowmin, out);  // colmin contiguous after rowmin
}

// Round 3
// 145.059 us; speedup vs baseline: 1.1517x; 1.1517x over previous
//
#include <hip/hip_runtime.h>
#include <hip/hip_bf16.h>

#define B_ 4
#define N_ 4096
#define D_ 128

typedef short short8 __attribute__((ext_vector_type(8)));
typedef float f32x4 __attribute__((ext_vector_type(4)));

#define SQRT2 1.41421356237309515f

// ---------------------------------------------------------------------------
// Kernel 1: fp32 -> bf16*sqrt(2) convert (RTN-E), row squared-norms (of the
// ORIGINAL values), init min arrays. One wave per row, grid-stride.
// blockIdx.y: 0=X, 1=Y.  Scaling by sqrt2 makes MFMA acc == 2*zz, saving one
// VALU op per P-element in the hot epilogue.
// ---------------------------------------------------------------------------
__global__ __launch_bounds__(256) void prep_kernel(
    const float* __restrict__ X, const float* __restrict__ Y,
    unsigned int* __restrict__ Xb, unsigned int* __restrict__ Yb,
    float* __restrict__ x2, float* __restrict__ y2,
    int* __restrict__ rowmin, int* __restrict__ colmin)
{
    const int which = blockIdx.y;
    const float* __restrict__ src = which ? Y : X;
    unsigned int* __restrict__ dst = which ? Yb : Xb;   // packed 2xbf16 per uint
    float* __restrict__ nrm = which ? y2 : x2;
    int* __restrict__ mn = which ? colmin : rowmin;

    const int wave = threadIdx.x >> 6, lane = threadIdx.x & 63;
    const int nwaves = gridDim.x * 4;
    for (int row = blockIdx.x * 4 + wave; row < B_ * N_; row += nwaves) {
        const float2 v = *(const float2*)(src + (size_t)row * D_ + lane * 2);
        float sq = fmaf(v.x, v.x, v.y * v.y);
        #pragma unroll
        for (int m = 1; m < 64; m <<= 1) sq += __shfl_xor(sq, m);

        // bf16 RTN-E of v*sqrt2, packed
        const unsigned ux = __float_as_uint(v.x * SQRT2);
        const unsigned uy = __float_as_uint(v.y * SQRT2);
        const unsigned rx = (ux + 0x7fffu + ((ux >> 16) & 1u)) >> 16;
        const unsigned ry = (uy + 0x7fffu + ((uy >> 16) & 1u)) >> 16;
        dst[(size_t)row * 64 + lane] = rx | (ry << 16);

        if (lane == 0) {
            nrm[row] = sq;
            mn[row] = 0x7f7fffff;   // +FLT_MAX bits; all mins >=0 so int order == float order
        }
    }
}

// ---------------------------------------------------------------------------
// Kernel 2: tiled bf16 MFMA distance + online min reduction.
// Block = 256 thr = 4 waves; block tile 128x128 output; full K=D=128 staged
// in LDS (X tile 32KB + Y tile 32KB = 64KB). XOR swizzle on 16B granules:
// granule g of row r stored at slot g^(r&7)  ->  frag ds_read_b128 is 2-way
// bank-aliased (free), staging writes coalesced & conflict-free.
// acc == 2*zz (inputs pre-scaled by sqrt2). P = x2 + y2 - acc.
// min/clamp commute (monotone): fold x2 (resp. y2) + clamp AFTER reduction.
//   A-frag: X[row0 + l16][kc + quad*8 + j]   (B-frag identical on Y)
//   C/D:    row = quad*4 + reg, col = l16    [m89-verified layout]
// ---------------------------------------------------------------------------
__global__ __launch_bounds__(256, 2) void chamfer_mfma(
    const unsigned short* __restrict__ Xb, const unsigned short* __restrict__ Yb,
    const float* __restrict__ x2, const float* __restrict__ y2,
    int* __restrict__ rowmin, int* __restrict__ colmin)
{
    __shared__ char smem[65536];
    char* ldsX = smem;            // [128 rows][16 granules of 16B], swizzled
    char* ldsY = smem + 32768;

    const int b = blockIdx.z;
    const int iT = blockIdx.y, jT = blockIdx.x;
    const int tid = threadIdx.x;
    const int wave = tid >> 6, lane = tid & 63;
    const int quad = lane >> 4, l16 = lane & 15;
    const int wr = wave >> 1, wc = wave & 1;
    const int rowBase = iT * 128 + wr * 64;   // global row of this wave's tile
    const int colBase = jT * 128 + wc * 64;

    const unsigned short* Xp = Xb + (size_t)b * N_ * D_;
    const unsigned short* Yp = Yb + (size_t)b * N_ * D_;

    // ---- stage: 2048 granules (16B) per matrix; 8 per thread per matrix ----
    // lin = it*256 + tid; row = lin>>4 (block-local), g = lin&15. Global reads
    // fully coalesced (consecutive lanes -> consecutive 16B).
    {
        uint4 tx[8], ty[8];
        const int rowT = iT * 128, colT = jT * 128;
        #pragma unroll
        for (int it = 0; it < 8; ++it) {
            const int lin = it * 256 + tid;
            const int r = lin >> 4, g = lin & 15;
            tx[it] = *(const uint4*)(Xp + (size_t)(rowT + r) * D_ + g * 8);
            ty[it] = *(const uint4*)(Yp + (size_t)(colT + r) * D_ + g * 8);
        }
        #pragma unroll
        for (int it = 0; it < 8; ++it) {
            const int lin = it * 256 + tid;
            const int r = lin >> 4, g = lin & 15;
            const int s = g ^ (r & 7);
            *(uint4*)(ldsX + r * 256 + s * 16) = tx[it];
            *(uint4*)(ldsY + r * 256 + s * 16) = ty[it];
        }
    }
    __syncthreads();

    f32x4 acc[4][4];
    #pragma unroll
    for (int i = 0; i < 4; i++)
        #pragma unroll
        for (int j = 0; j < 4; j++)
            acc[i][j] = (f32x4){0.f, 0.f, 0.f, 0.f};

    const int sw = l16 & 7;
    const int rowL = wr * 64;   // block-local row base of this wave
    const int colL = wc * 64;

    #pragma unroll
    for (int kcIdx = 0; kcIdx < 4; ++kcIdx) {
        const int g = kcIdx * 4 + quad;          // granule wanted (koff = g*8 elems)
        const int s16 = (g ^ sw) * 16;
        short8 af[4], bfv[4];
        #pragma unroll
        for (int rt = 0; rt < 4; rt++)
            af[rt] = *(const short8*)(ldsX + (rowL + rt * 16 + l16) * 256 + s16);
        #pragma unroll
        for (int ct = 0; ct < 4; ct++)
            bfv[ct] = *(const short8*)(ldsY + (colL + ct * 16 + l16) * 256 + s16);
        #pragma unroll
        for (int rt = 0; rt < 4; rt++)
            #pragma unroll
            for (int ct = 0; ct < 4; ct++)
                acc[rt][ct] = __builtin_amdgcn_mfma_f32_16x16x32_bf16(
                    af[rt], bfv[ct], acc[rt][ct], 0, 0, 0);
    }

    // ---- epilogue: rmin(rt,i) = min_ct,l16 (y2[col] - acc); cmin(ct,l16) =
    //      min_rt,i,quad (x2[row] - acc); fold x2/y2 + clamp after reduce ----
    float x2v[4][4];   // row = rowBase + rt*16 + quad*4 + i
    #pragma unroll
    for (int rt = 0; rt < 4; rt++)
        #pragma unroll
        for (int i = 0; i < 4; i++)
            x2v[rt][i] = x2[(size_t)b * N_ + rowBase + rt * 16 + quad * 4 + i];
    float y2v[4];      // col = colBase + ct*16 + l16
    #pragma unroll
    for (int ct = 0; ct < 4; ct++)
        y2v[ct] = y2[(size_t)b * N_ + colBase + ct * 16 + l16];

    float rmin[4][4];
    float cmin[4];
    #pragma unroll
    for (int ct = 0; ct < 4; ct++) cmin[ct] = 3.0e38f;
    #pragma unroll
    for (int rt = 0; rt < 4; rt++)
        #pragma unroll
        for (int i = 0; i < 4; i++) {
            float rm = 3.0e38f;
            const float xv = x2v[rt][i];
            #pragma unroll
            for (int ct = 0; ct < 4; ct++) {
                const float a = acc[rt][ct][i];
                rm = fminf(rm, y2v[ct] - a);
                cmin[ct] = fminf(cmin[ct], xv - a);
            }
            rmin[rt][i] = rm;
        }

    // rowmin: reduce over the 16 lanes of the quad (covers 64 cols w/ ct)
    #pragma unroll
    for (int rt = 0; rt < 4; rt++)
        #pragma unroll
        for (int i = 0; i < 4; i++) {
            float v = rmin[rt][i];
            #pragma unroll
            for (int m = 1; m < 16; m <<= 1) v = fminf(v, __shfl_xor(v, m));
            rmin[rt][i] = v;
        }
    if (l16 == 0) {
        #pragma unroll
        for (int rt = 0; rt < 4; rt++)
            #pragma unroll
            for (int i = 0; i < 4; i++) {
                float v = fminf(fmaxf(x2v[rt][i] + rmin[rt][i], 0.0f), 100.0f);
                atomicMin(&rowmin[(size_t)b * N_ + rowBase + rt * 16 + quad * 4 + i],
                          __float_as_int(v));
            }
    }

    // colmin: reduce across quads (covers 64 rows w/ rt,i)
    #pragma unroll
    for (int ct = 0; ct < 4; ct++) {
        float v = cmin[ct];
        v = fminf(v, __shfl_xor(v, 16));
        v = fminf(v, __shfl_xor(v, 32));
        cmin[ct] = v;
    }
    if (quad == 0) {
        #pragma unroll
        for (int ct = 0; ct < 4; ct++) {
            float v = fminf(fmaxf(y2v[ct] + cmin[ct], 0.0f), 100.0f);
            atomicMin(&colmin[(size_t)b * N_ + colBase + ct * 16 + l16],
                      __float_as_int(v));
        }
    }
}

// ---------------------------------------------------------------------------
// Kernel 3: final mean. mins = rowmin (B_*N_) followed immediately by
// colmin (B_*N_).  out = (sum_rowmin + sum_colmin) / (B*N) / B
// ---------------------------------------------------------------------------
__global__ __launch_bounds__(256) void finalize_kernel(
    const int* __restrict__ mins, float* __restrict__ out)
{
    float s = 0.f;
    const int4* p = (const int4*)mins;
    const int n4 = (2 * B_ * N_) / 4;
    for (int i = threadIdx.x; i < n4; i += 256) {
        int4 v = p[i];
        s += __int_as_float(v.x) + __int_as_float(v.y) +
             __int_as_float(v.z) + __int_as_float(v.w);
    }
    #pragma unroll
    for (int m = 1; m < 64; m <<= 1) s += __shfl_xor(s, m);
    __shared__ float sm[4];
    if ((threadIdx.x & 63) == 0) sm[threadIdx.x >> 6] = s;
    __syncthreads();
    if (threadIdx.x == 0)
        out[0] = (sm[0] + sm[1] + sm[2] + sm[3]) / ((float)B_ * (float)N_) / (float)B_;
}

extern "C" void kernel_launch(void* const* d_in, const int* in_sizes, int n_in,
                              void* d_out, int out_size, void* d_ws, size_t ws_size,
                              hipStream_t stream) {
    const float* X = (const float*)d_in[0];   // corr_pred   [B,N,D] fp32
    const float* Y = (const float*)d_in[1];   // corr_target [B,N,D] fp32

    char* ws = (char*)d_ws;
    const size_t bf_bytes = (size_t)B_ * N_ * D_ * 2;   // 4 MB each
    unsigned short* Xb = (unsigned short*)ws;
    unsigned short* Yb = (unsigned short*)(ws + bf_bytes);
    char* ws2 = ws + 2 * bf_bytes;
    const size_t vec_bytes = (size_t)B_ * N_ * 4;       // 64 KB each
    float* x2     = (float*)(ws2);
    float* y2     = (float*)(ws2 + vec_bytes);
    int*   rowmin = (int*)  (ws2 + 2 * vec_bytes);
    int*   colmin = (int*)  (ws2 + 3 * vec_bytes);      // contiguous after rowmin
    float* out = (float*)d_out;

    prep_kernel<<<dim3(512, 2), 256, 0, stream>>>(
        X, Y, (unsigned int*)Xb, (unsigned int*)Yb, x2, y2, rowmin, colmin);
    chamfer_mfma<<<dim3(N_ / 128, N_ / 128, B_), 256, 0, stream>>>(
        Xb, Yb, x2, y2, rowmin, colmin);
    finalize_kernel<<<1, 256, 0, stream>>>(rowmin, out);  // colmin contiguous after rowmin
}

// Round 4
// 126.775 us; speedup vs baseline: 1.3179x; 1.1442x over previous
//
#include <hip/hip_runtime.h>
#include <hip/hip_bf16.h>

#define B_ 4
#define N_ 4096
#define D_ 128
#define EPB (N_ * D_)   // elems per batch in packed layout = 524288

typedef short short8 __attribute__((ext_vector_type(8)));
typedef float f32x4 __attribute__((ext_vector_type(4)));

#define SQRT2 1.41421356237309515f

// ---------------------------------------------------------------------------
// Packed fragment-major layout (per batch):
//   elem(row, k) -> (row>>4)*2048 + (k>>3)*128 + (row&15)*8 + (k&7)
// A wave's MFMA fragment for 16-row group rg at k-chunk kc is then the
// contiguous 1KB range [rg*2048 + kc*16 + lane*8, +8) -- one coalesced
// global_load_dwordx4 per wave, no LDS needed.
// ---------------------------------------------------------------------------

// Kernel 1: fp32 -> bf16*sqrt2 (RTN-E) into packed layout, row norms, min init.
// One wave per row, grid-stride. blockIdx.y: 0=X, 1=Y.
__global__ __launch_bounds__(256) void prep_kernel(
    const float* __restrict__ X, const float* __restrict__ Y,
    unsigned short* __restrict__ Xb, unsigned short* __restrict__ Yb,
    float* __restrict__ x2, float* __restrict__ y2,
    int* __restrict__ rowmin, int* __restrict__ colmin)
{
    const int which = blockIdx.y;
    const float* __restrict__ src = which ? Y : X;
    unsigned short* __restrict__ dst = which ? Yb : Xb;
    float* __restrict__ nrm = which ? y2 : x2;
    int* __restrict__ mn = which ? colmin : rowmin;

    const int wave = threadIdx.x >> 6, lane = threadIdx.x & 63;
    const int nwaves = gridDim.x * 4;
    for (int row = blockIdx.x * 4 + wave; row < B_ * N_; row += nwaves) {
        const float2 v = *(const float2*)(src + (size_t)row * D_ + lane * 2);
        float sq = fmaf(v.x, v.x, v.y * v.y);
        #pragma unroll
        for (int m = 1; m < 64; m <<= 1) sq += __shfl_xor(sq, m);

        // bf16 RTN-E of v*sqrt2, packed pair (k = 2*lane, 2*lane+1)
        const unsigned ux = __float_as_uint(v.x * SQRT2);
        const unsigned uy = __float_as_uint(v.y * SQRT2);
        const unsigned rx = (ux + 0x7fffu + ((ux >> 16) & 1u)) >> 16;
        const unsigned ry = (uy + 0x7fffu + ((uy >> 16) & 1u)) >> 16;

        const int b  = row >> 12;            // row / N_
        const int rn = row & (N_ - 1);
        const int rg = rn >> 4, r = rn & 15;
        // k = 2*lane: g = lane>>2, within-granule byte pair = lane&3
        const size_t elem = (size_t)b * EPB + rg * 2048 + (lane >> 2) * 128
                          + r * 8 + (lane & 3) * 2;
        *(unsigned int*)(dst + elem) = rx | (ry << 16);

        if (lane == 0) {
            nrm[row] = sq;
            mn[row] = 0x7f7fffff;   // +FLT_MAX bits (all mins >= 0)
        }
    }
}

// ---------------------------------------------------------------------------
// Kernel 2: MFMA chamfer tiles, NO LDS, NO barriers. Block = 4 independent
// waves, each owning a 64x64 output tile of the 128x128 block tile.
// Fragments load coalesced from the packed layout; K-loop double-buffered in
// registers. acc == 2*zz (inputs pre-scaled); P = x2 + y2 - acc; clamp and
// norm folds applied after the min-reductions (monotone, they commute).
//   C/D layout: row = quad*4 + reg, col = l16   [m89-verified]
// Grid: x = iT (fastest) so the concurrent dispatch window shares one jT
// (Y tile) per XCD L2.
// ---------------------------------------------------------------------------
__global__ __launch_bounds__(256, 3) void chamfer_mfma(
    const unsigned short* __restrict__ Xb, const unsigned short* __restrict__ Yb,
    const float* __restrict__ x2, const float* __restrict__ y2,
    int* __restrict__ rowmin, int* __restrict__ colmin)
{
    const int b = blockIdx.z;
    const int iT = blockIdx.x, jT = blockIdx.y;
    const int tid = threadIdx.x;
    const int wave = tid >> 6, lane = tid & 63;
    const int quad = lane >> 4, l16 = lane & 15;
    const int wr = wave >> 1, wc = wave & 1;
    const int rowBase = iT * 128 + wr * 64;
    const int colBase = jT * 128 + wc * 64;

    const unsigned short* __restrict__ Xp = Xb + (size_t)b * EPB;
    const unsigned short* __restrict__ Yp = Yb + (size_t)b * EPB;

    // fragment base pointers: row-group (rowBase/16 + rt), lane-linear
    const unsigned short* ap[4];
    const unsigned short* bp[4];
    #pragma unroll
    for (int rt = 0; rt < 4; rt++) {
        ap[rt] = Xp + ((rowBase >> 4) + rt) * 2048 + lane * 8;
        bp[rt] = Yp + ((colBase >> 4) + rt) * 2048 + lane * 8;
    }

    // prefetch epilogue norms early (independent of MFMA chain)
    float x2v[4][4];   // row = rowBase + rt*16 + quad*4 + i
    #pragma unroll
    for (int rt = 0; rt < 4; rt++)
        #pragma unroll
        for (int i = 0; i < 4; i++)
            x2v[rt][i] = x2[(size_t)b * N_ + rowBase + rt * 16 + quad * 4 + i];
    float y2v[4];      // col = colBase + ct*16 + l16
    #pragma unroll
    for (int ct = 0; ct < 4; ct++)
        y2v[ct] = y2[(size_t)b * N_ + colBase + ct * 16 + l16];

    f32x4 acc[4][4];
    #pragma unroll
    for (int i = 0; i < 4; i++)
        #pragma unroll
        for (int j = 0; j < 4; j++)
            acc[i][j] = (f32x4){0.f, 0.f, 0.f, 0.f};

    // K-loop: 4 chunks of 32 (kc*16 elem offset per chunk), reg double-buffer
    short8 af[2][4], bf[2][4];
    #pragma unroll
    for (int rt = 0; rt < 4; rt++) {
        af[0][rt] = *(const short8*)(ap[rt]);
        bf[0][rt] = *(const short8*)(bp[rt]);
    }
    #pragma unroll
    for (int kc = 0; kc < 4; ++kc) {
        const int cur = kc & 1, nxt = cur ^ 1;
        if (kc < 3) {
            const int off = (kc + 1) * 512;   // 32 k-elems * 16 rows = 512 elems
            #pragma unroll
            for (int rt = 0; rt < 4; rt++) {
                af[nxt][rt] = *(const short8*)(ap[rt] + off);
                bf[nxt][rt] = *(const short8*)(bp[rt] + off);
            }
        }
        #pragma unroll
        for (int rt = 0; rt < 4; rt++)
            #pragma unroll
            for (int ct = 0; ct < 4; ct++)
                acc[rt][ct] = __builtin_amdgcn_mfma_f32_16x16x32_bf16(
                    af[cur][rt], bf[cur][ct], acc[rt][ct], 0, 0, 0);
    }

    // ---- epilogue: rmin = min_ct(y2 - acc); cmin = min_rt,i(x2 - acc) ----
    float rmin[4][4];
    float cmin[4];
    #pragma unroll
    for (int ct = 0; ct < 4; ct++) cmin[ct] = 3.0e38f;
    #pragma unroll
    for (int rt = 0; rt < 4; rt++)
        #pragma unroll
        for (int i = 0; i < 4; i++) {
            float rm = 3.0e38f;
            const float xv = x2v[rt][i];
            #pragma unroll
            for (int ct = 0; ct < 4; ct++) {
                const float a = acc[rt][ct][i];
                rm = fminf(rm, y2v[ct] - a);
                cmin[ct] = fminf(cmin[ct], xv - a);
            }
            rmin[rt][i] = rm;
        }

    // rowmin: reduce across the 16 lanes of each quad
    #pragma unroll
    for (int rt = 0; rt < 4; rt++)
        #pragma unroll
        for (int i = 0; i < 4; i++) {
            float v = rmin[rt][i];
            #pragma unroll
            for (int m = 1; m < 16; m <<= 1) v = fminf(v, __shfl_xor(v, m));
            rmin[rt][i] = v;
        }
    if (l16 == 0) {
        #pragma unroll
        for (int rt = 0; rt < 4; rt++)
            #pragma unroll
            for (int i = 0; i < 4; i++) {
                float v = fminf(fmaxf(x2v[rt][i] + rmin[rt][i], 0.0f), 100.0f);
                atomicMin(&rowmin[(size_t)b * N_ + rowBase + rt * 16 + quad * 4 + i],
                          __float_as_int(v));
            }
    }

    // colmin: reduce across quads
    #pragma unroll
    for (int ct = 0; ct < 4; ct++) {
        float v = cmin[ct];
        v = fminf(v, __shfl_xor(v, 16));
        v = fminf(v, __shfl_xor(v, 32));
        cmin[ct] = v;
    }
    if (quad == 0) {
        #pragma unroll
        for (int ct = 0; ct < 4; ct++) {
            float v = fminf(fmaxf(y2v[ct] + cmin[ct], 0.0f), 100.0f);
            atomicMin(&colmin[(size_t)b * N_ + colBase + ct * 16 + l16],
                      __float_as_int(v));
        }
    }
}

// ---------------------------------------------------------------------------
// Kernel 3: final mean over rowmin (B_*N_) ++ colmin (B_*N_), contiguous.
// out = (sum_rowmin + sum_colmin) / (B*N) / B
// ---------------------------------------------------------------------------
__global__ __launch_bounds__(1024) void finalize_kernel(
    const int* __restrict__ mins, float* __restrict__ out)
{
    float s = 0.f;
    const int4* p = (const int4*)mins;
    const int n4 = (2 * B_ * N_) / 4;
    for (int i = threadIdx.x; i < n4; i += 1024) {
        int4 v = p[i];
        s += __int_as_float(v.x) + __int_as_float(v.y) +
             __int_as_float(v.z) + __int_as_float(v.w);
    }
    #pragma unroll
    for (int m = 1; m < 64; m <<= 1) s += __shfl_xor(s, m);
    __shared__ float sm[16];
    if ((threadIdx.x & 63) == 0) sm[threadIdx.x >> 6] = s;
    __syncthreads();
    if (threadIdx.x == 0) {
        float t = 0.f;
        #pragma unroll
        for (int i = 0; i < 16; i++) t += sm[i];
        out[0] = t / ((float)B_ * (float)N_) / (float)B_;
    }
}

extern "C" void kernel_launch(void* const* d_in, const int* in_sizes, int n_in,
                              void* d_out, int out_size, void* d_ws, size_t ws_size,
                              hipStream_t stream) {
    const float* X = (const float*)d_in[0];   // corr_pred   [B,N,D] fp32
    const float* Y = (const float*)d_in[1];   // corr_target [B,N,D] fp32

    char* ws = (char*)d_ws;
    const size_t bf_bytes = (size_t)B_ * N_ * D_ * 2;   // 4 MB each (packed)
    unsigned short* Xb = (unsigned short*)ws;
    unsigned short* Yb = (unsigned short*)(ws + bf_bytes);
    char* ws2 = ws + 2 * bf_bytes;
    const size_t vec_bytes = (size_t)B_ * N_ * 4;       // 64 KB each
    float* x2     = (float*)(ws2);
    float* y2     = (float*)(ws2 + vec_bytes);
    int*   rowmin = (int*)  (ws2 + 2 * vec_bytes);
    int*   colmin = (int*)  (ws2 + 3 * vec_bytes);      // contiguous after rowmin
    float* out = (float*)d_out;

    prep_kernel<<<dim3(512, 2), 256, 0, stream>>>(
        X, Y, Xb, Yb, x2, y2, rowmin, colmin);
    chamfer_mfma<<<dim3(N_ / 128, N_ / 128, B_), 256, 0, stream>>>(
        Xb, Yb, x2, y2, rowmin, colmin);
    finalize_kernel<<<1, 1024, 0, stream>>>(rowmin, out);  // colmin contiguous
}